// Round 1
// 490.561 us; speedup vs baseline: 1.0008x; 1.0008x over previous
//
#include <hip/hip_runtime.h>
#include <hip/hip_bf16.h>
#include <stdint.h>

// Problem constants (B=4, T=1024, D=1024, E=8, HD=4096)
#define NE 8
#define DIM 1024
#define HDIM 4096
#define NTOK 4096
#define KSPLIT 4
#define MAXT 40   // max occupied 128-row m-tiles: 32 full + 8 partial

typedef unsigned short ushort_t;
typedef __attribute__((ext_vector_type(4))) float f32x4;
typedef __attribute__((ext_vector_type(8))) short bf16x8;
typedef __attribute__((ext_vector_type(8))) ushort_t u16x8;

// RNE float -> bf16 bits
__device__ __forceinline__ ushort_t f2b(float f) {
  union { float f; unsigned u; } c; c.f = f;
  unsigned u = c.u;
  return (ushort_t)((u + 0x7fffu + ((u >> 16) & 1u)) >> 16);
}

// truncate-pack 2 fp32 -> 2 bf16 in one dword via v_perm (matches prior cvt8 numerics)
__device__ __forceinline__ unsigned pk2(float a, float b) {
  union { float f; unsigned u; } x, y; x.f = a; y.f = b;
  return __builtin_amdgcn_perm(y.u, x.u, 0x07060302);
}

// async global->LDS, 16 bytes per lane; LDS dest = wave-uniform base + lane*16
__device__ __forceinline__ void gl2lds16(const void* g, void* l) {
  __builtin_amdgcn_global_load_lds(
      (__attribute__((address_space(1))) void*)g,
      (__attribute__((address_space(3))) void*)l, 16, 0, 0);
}

// ---------------- router: logits fp32 + argmax + count (fused) --------------
__global__ __launch_bounds__(256) void router_kernel(
    const float* __restrict__ x, const float* __restrict__ rw,
    int* __restrict__ eid, int* __restrict__ rank, int* __restrict__ cnt) {
  __shared__ float w[NE * 1028];  // stride 1028 to spread LDS banks
  for (int i = threadIdx.x; i < NE * DIM; i += 256) {
    int e = i >> 10, d = i & 1023;
    w[e * 1028 + d] = rw[i];
  }
  __syncthreads();
  int grp = threadIdx.x >> 3;   // 32 tokens / block
  int e = threadIdx.x & 7;      // one expert per lane-in-group
  int t = blockIdx.x * 32 + grp;
  const float4* xr = (const float4*)(x + (size_t)t * DIM);
  const float4* wr = (const float4*)(w + e * 1028);
  float acc = 0.f;
#pragma unroll 4
  for (int i = 0; i < DIM / 4; ++i) {
    float4 xv = xr[i], wv = wr[i];
    acc += xv.x * wv.x + xv.y * wv.y + xv.z * wv.z + xv.w * wv.w;
  }
  float v = acc; int ie = e;
#pragma unroll
  for (int m = 4; m; m >>= 1) {
    float ov = __shfl_xor(v, m, 8);
    int oi = __shfl_xor(ie, m, 8);
    if (ov > v || (ov == v && oi < ie)) { v = ov; ie = oi; }
  }
  if (e == 0) {
    eid[t] = ie;
    rank[t] = atomicAdd(&cnt[ie], 1);
  }
}

// prefix-sum + build dense m-tile table (expert id, row offset within expert)
__global__ void scan_kernel(const int* __restrict__ cnt, int* __restrict__ offs,
                            int* __restrict__ tile_e, int* __restrict__ tile_m,
                            int* __restrict__ ntiles) {
  if (threadIdx.x == 0) {
    int s = 0, nt = 0;
    for (int e = 0; e < NE; ++e) {
      offs[e] = s;
      int c = cnt[e];
      for (int m = 0; m < c; m += 128) { tile_e[nt] = e; tile_m[nt] = m; ++nt; }
      s += c;
    }
    offs[NE] = s;
    *ntiles = nt;
  }
}

// one block per token: write sorted[] and gather x row -> bf16 grouped matrix
__global__ __launch_bounds__(256) void gather_kernel(
    const float* __restrict__ x, const int* __restrict__ eid,
    const int* __restrict__ rank, const int* __restrict__ offs,
    int* __restrict__ sorted, ushort_t* __restrict__ Xg) {
  int t = blockIdx.x;
  int e = eid[t];
  int pos = offs[e] + rank[t];
  if (threadIdx.x == 0) sorted[pos] = t;
  int i = threadIdx.x;  // 256 threads, 4 floats each
  float4 v = ((const float4*)(x + (size_t)t * DIM))[i];
  ushort4 o = make_ushort4(f2b(v.x), f2b(v.y), f2b(v.z), f2b(v.w));
  *(ushort4*)(Xg + (size_t)pos * DIM + i * 4) = o;
}

// ---------------- weight conversion ----------------------------------------
// fc[e][d][h] fp32 -> fct[e][h][d] bf16. 64x64 tiles, float4 reads, 16B writes.
__global__ __launch_bounds__(256) void transpose_fc_kernel(
    const float* __restrict__ fc, ushort_t* __restrict__ fct) {
  __shared__ float tile[64][68];  // pad 68: write-side col reads spread banks
  int e = blockIdx.z;
  int h0 = blockIdx.x * 64, d0 = blockIdx.y * 64;
  int tid = threadIdx.x;
  // read: 64 d-rows x 64 h, fully coalesced float4 (16 lanes/row)
  int rr = tid >> 4;          // 0..15
  int cc = (tid & 15) * 4;    // 0..60
  const float* src = fc + ((size_t)e * DIM + d0 + rr) * HDIM + h0 + cc;
#pragma unroll
  for (int i = 0; i < 4; ++i) {
    float4 v = *(const float4*)(src + (size_t)(i * 16) * HDIM);
    *(float4*)&tile[rr + i * 16][cc] = v;
  }
  __syncthreads();
  // write: 64 h-rows x 64 d bf16; 4 lanes cover 128B contiguous
  int hr = tid >> 2;          // 0..63
  int dseg = (tid & 3) * 16;  // 0,16,32,48
  union { ushort_t s[16]; u16x8 v[2]; } o;
#pragma unroll
  for (int j = 0; j < 16; ++j) o.s[j] = f2b(tile[dseg + j][hr]);
  ushort_t* dst = fct + ((size_t)e * HDIM + h0 + hr) * DIM + d0 + dseg;
  *(u16x8*)dst = o.v[0];
  *(u16x8*)(dst + 8) = o.v[1];
}

// ---------------- GEMM1: H = relu(Xg @ fct^T)^2, bf16 out -------------------
// C-tile 128x128, 4 waves (2x2), each wave 64x64 = 4x4 of 16x16x32 MFMA.
// 2-phase pipeline: stage tile t+1 (gl2lds) BEFORE computing tile t; the
// single vmcnt(0)+barrier at iteration end then overlaps load latency with
// the ds_read+MFMA phase (T3-minimum recipe).
__global__ __launch_bounds__(256, 2) void gemm1_kernel(
    const ushort_t* __restrict__ Xg, const ushort_t* __restrict__ fct,
    const int* __restrict__ offs, const int* __restrict__ tile_e,
    const int* __restrict__ tile_m, const int* __restrict__ ntiles,
    ushort_t* __restrict__ H) {
  if ((int)blockIdx.y >= *ntiles) return;
  int e = tile_e[blockIdx.y];
  int mb = tile_m[blockIdx.y];   // row offset within expert
  int m0 = offs[e];
  int Me = offs[e + 1] - m0;
  int n0 = blockIdx.x * 128;

  __shared__ ushort_t As[2][128 * 32];
  __shared__ ushort_t Bs[2][128 * 32];

  int tid = threadIdx.x;
  int wave = tid >> 6;
  int lane = tid & 63;

  const ushort_t* ap[2]; const ushort_t* bp[2];
  int soff[2];
#pragma unroll
  for (int q = 0; q < 2; ++q) {
    int rl = (wave * 2 + q) * 16 + (lane >> 2);
    int kc = (lane & 3) * 8;
    int rg = mb + rl; if (rg >= Me) rg = Me - 1;  // clamp tail rows
    ap[q] = Xg + (size_t)(m0 + rg) * DIM + kc;
    bp[q] = fct + ((size_t)e * HDIM + n0 + rl) * DIM + kc;
    soff[q] = (wave * 2 + q) * 512;
  }

  f32x4 acc[4][4] = {};
  int wm = (wave & 1) * 64;
  int wn = (wave >> 1) * 64;
  int fr = lane & 15;
  int kq = (lane >> 4) * 8;

  // prologue: stage k=0 into buffer 0
  gl2lds16(ap[0], &As[0][soff[0]]);
  gl2lds16(ap[1], &As[0][soff[1]]);
  gl2lds16(bp[0], &Bs[0][soff[0]]);
  gl2lds16(bp[1], &Bs[0][soff[1]]);
  __syncthreads();

  int cur = 0;
  for (int k0 = 0; k0 < DIM; k0 += 32) {
    int cn = cur ^ 1;
    if (k0 + 32 < DIM) {  // stage NEXT tile first (loads fly during compute)
      gl2lds16(ap[0] + k0 + 32, &As[cn][soff[0]]);
      gl2lds16(ap[1] + k0 + 32, &As[cn][soff[1]]);
      gl2lds16(bp[0] + k0 + 32, &Bs[cn][soff[0]]);
      gl2lds16(bp[1] + k0 + 32, &Bs[cn][soff[1]]);
    }
    bf16x8 af[4], bf[4];
#pragma unroll
    for (int i = 0; i < 4; ++i) {
      af[i] = *(const bf16x8*)&As[cur][(wm + i * 16 + fr) * 32 + kq];
      bf[i] = *(const bf16x8*)&Bs[cur][(wn + i * 16 + fr) * 32 + kq];
    }
#pragma unroll
    for (int i = 0; i < 4; ++i)
#pragma unroll
      for (int j = 0; j < 4; ++j)
        acc[i][j] = __builtin_amdgcn_mfma_f32_16x16x32_bf16(af[i], bf[j], acc[i][j], 0, 0, 0);
    __syncthreads();  // drains vmcnt(0): next-tile stage had MFMA-phase to land
    cur = cn;
  }

  int cq = (lane >> 4) * 4;
#pragma unroll
  for (int i = 0; i < 4; ++i) {
#pragma unroll
    for (int r = 0; r < 4; ++r) {
      int rl = wm + i * 16 + cq + r;
      int rg = mb + rl;
      if (rg < Me) {
        ushort_t* dst = H + (size_t)(m0 + rg) * HDIM + n0 + wn + (lane & 15);
#pragma unroll
        for (int j = 0; j < 4; ++j) {
          float v = acc[i][j][r];
          v = fmaxf(v, 0.f);
          dst[j * 16] = f2b(v * v);
        }
      }
    }
  }
}

// ---------------- GEMM2: P[ks] = H @ proj^T (K-slice), no atomics -----------
// B (proj fp32) is reg-staged: global loads issued at loop top (T14 issue-early),
// truncate-packed to bf16 and ds_written AFTER the MFMA cluster (write-late).
// LDS B is now bf16 [128][32] (same layout as A): dbuf fits in 32KB total,
// frag reads are plain b128, and the chunked write mapping (consecutive lanes
// -> consecutive 16B) is bank-conflict-free.
__global__ __launch_bounds__(256, 2) void gemm2_kernel(
    const ushort_t* __restrict__ Hm, const float* __restrict__ pj,
    const int* __restrict__ offs, const int* __restrict__ tile_e,
    const int* __restrict__ tile_m, const int* __restrict__ ntiles,
    float* __restrict__ P) {
  if ((int)blockIdx.y >= *ntiles) return;
  int e = tile_e[blockIdx.y];
  int mb = tile_m[blockIdx.y];
  int ks = blockIdx.z;
  int m0 = offs[e];
  int Me = offs[e + 1] - m0;
  int n0 = blockIdx.x * 128;

  __shared__ ushort_t As[2][128 * 32];
  __shared__ ushort_t Bs[2][128 * 32];

  int tid = threadIdx.x;
  int wave = tid >> 6;
  int lane = tid & 63;

  // A staging: async 16B, 2 chunks/thread
  const ushort_t* ap[2]; int soff[2];
#pragma unroll
  for (int q = 0; q < 2; ++q) {
    int rl = (wave * 2 + q) * 16 + (lane >> 2);
    int kc = (lane & 3) * 8;
    int rg = mb + rl; if (rg >= Me) rg = Me - 1;
    ap[q] = Hm + (size_t)(m0 + rg) * HDIM + kc;
    soff[q] = (wave * 2 + q) * 512;
  }

  // B staging: thread owns rows {br, br+64}, 8 k each; lanes write contiguous 16B
  int br = tid >> 2;          // 0..63
  int bk = (tid & 3) * 8;     // 0,8,16,24
  const float* bsrc0 = pj + ((size_t)e * DIM + n0 + br) * HDIM + bk;
  const float* bsrc1 = bsrc0 + (size_t)64 * HDIM;
  int boff0 = br * 32 + bk;
  int boff1 = (br + 64) * 32 + bk;

  f32x4 acc[4][4] = {};
  int wm = (wave & 1) * 64;
  int wn = (wave >> 1) * 64;
  int fr = lane & 15;
  int kq = (lane >> 4) * 8;

  int kbeg = ks * (HDIM / KSPLIT);
  int kend = kbeg + (HDIM / KSPLIT);

  float4 bv[4];
  // prologue: stage k=kbeg into buffer 0
  bv[0] = *(const float4*)(bsrc0 + kbeg);
  bv[1] = *(const float4*)(bsrc0 + kbeg + 4);
  bv[2] = *(const float4*)(bsrc1 + kbeg);
  bv[3] = *(const float4*)(bsrc1 + kbeg + 4);
  gl2lds16(ap[0] + kbeg, &As[0][soff[0]]);
  gl2lds16(ap[1] + kbeg, &As[0][soff[1]]);
  {
    union { unsigned u[4]; bf16x8 v; } w;
    w.u[0] = pk2(bv[0].x, bv[0].y); w.u[1] = pk2(bv[0].z, bv[0].w);
    w.u[2] = pk2(bv[1].x, bv[1].y); w.u[3] = pk2(bv[1].z, bv[1].w);
    *(bf16x8*)&Bs[0][boff0] = w.v;
    w.u[0] = pk2(bv[2].x, bv[2].y); w.u[1] = pk2(bv[2].z, bv[2].w);
    w.u[2] = pk2(bv[3].x, bv[3].y); w.u[3] = pk2(bv[3].z, bv[3].w);
    *(bf16x8*)&Bs[0][boff1] = w.v;
  }
  __syncthreads();

  int cur = 0;
  for (int k0 = kbeg; k0 < kend; k0 += 32) {
    int cn = cur ^ 1;
    bool more = (k0 + 32) < kend;
    if (more) {  // issue next-tile loads early: B into regs, A direct to LDS
      bv[0] = *(const float4*)(bsrc0 + k0 + 32);
      bv[1] = *(const float4*)(bsrc0 + k0 + 36);
      bv[2] = *(const float4*)(bsrc1 + k0 + 32);
      bv[3] = *(const float4*)(bsrc1 + k0 + 36);
      gl2lds16(ap[0] + k0 + 32, &As[cn][soff[0]]);
      gl2lds16(ap[1] + k0 + 32, &As[cn][soff[1]]);
    }
    bf16x8 af[4], bf[4];
#pragma unroll
    for (int i = 0; i < 4; ++i) {
      af[i] = *(const bf16x8*)&As[cur][(wm + i * 16 + fr) * 32 + kq];
      bf[i] = *(const bf16x8*)&Bs[cur][(wn + i * 16 + fr) * 32 + kq];
    }
#pragma unroll
    for (int i = 0; i < 4; ++i)
#pragma unroll
      for (int j = 0; j < 4; ++j)
        acc[i][j] = __builtin_amdgcn_mfma_f32_16x16x32_bf16(af[i], bf[j], acc[i][j], 0, 0, 0);
    if (more) {  // write-late: B loads had the whole MFMA cluster to land
      union { unsigned u[4]; bf16x8 v; } w;
      w.u[0] = pk2(bv[0].x, bv[0].y); w.u[1] = pk2(bv[0].z, bv[0].w);
      w.u[2] = pk2(bv[1].x, bv[1].y); w.u[3] = pk2(bv[1].z, bv[1].w);
      *(bf16x8*)&Bs[cn][boff0] = w.v;
      w.u[0] = pk2(bv[2].x, bv[2].y); w.u[1] = pk2(bv[2].z, bv[2].w);
      w.u[2] = pk2(bv[3].x, bv[3].y); w.u[3] = pk2(bv[3].z, bv[3].w);
      *(bf16x8*)&Bs[cn][boff1] = w.v;
    }
    __syncthreads();
    cur = cn;
  }

  int cq = (lane >> 4) * 4;
#pragma unroll
  for (int i = 0; i < 4; ++i) {
#pragma unroll
    for (int r = 0; r < 4; ++r) {
      int rl = wm + i * 16 + cq + r;
      int rg = mb + rl;
      if (rg < Me) {
        float* dst = P + ((size_t)ks * NTOK + (m0 + rg)) * DIM + n0 + wn + (lane & 15);
#pragma unroll
        for (int j = 0; j < 4; ++j) dst[j * 16] = acc[i][j][r];
      }
    }
  }
}

// ---------------- reduce: out[tok] = sum_ks P[ks][pos], coalesced -----------
__global__ __launch_bounds__(256) void reduce_kernel(
    const float* __restrict__ P, const int* __restrict__ sorted,
    float* __restrict__ out) {
  int pos = blockIdx.x;
  int tok = sorted[pos];
  int i = threadIdx.x;
  size_t base = (size_t)pos * DIM + i * 4;
  const size_t S = (size_t)NTOK * DIM;
  f32x4 s = *(const f32x4*)(P + base) + *(const f32x4*)(P + S + base) +
            *(const f32x4*)(P + 2 * S + base) + *(const f32x4*)(P + 3 * S + base);
  *(f32x4*)(out + (size_t)tok * DIM + i * 4) = s;
}

// ---------------- launch -----------------------------------------------------
extern "C" void kernel_launch(void* const* d_in, const int* in_sizes, int n_in,
                              void* d_out, int out_size, void* d_ws, size_t ws_size,
                              hipStream_t stream) {
  const float* x  = (const float*)d_in[0];
  const float* rw = (const float*)d_in[1];
  const float* fc = (const float*)d_in[2];
  const float* pj = (const float*)d_in[3];
  float* out = (float*)d_out;
  char* ws = (char*)d_ws;

  // workspace layout (~106 MiB, same footprint as prior rounds)
  int* eid        = (int*)(ws + 0x0000);       // 16KB
  int* rank       = (int*)(ws + 0x4000);       // 16KB
  int* cnt        = (int*)(ws + 0x8000);       // 32B
  int* offs       = (int*)(ws + 0x8100);       // 36B
  int* tile_e     = (int*)(ws + 0x8200);       // 160B
  int* tile_m     = (int*)(ws + 0x8600);       // 160B
  int* ntiles     = (int*)(ws + 0x8a00);       // 4B
  int* sorted     = (int*)(ws + 0x9000);       // 16KB
  ushort_t* Xg    = (ushort_t*)(ws + 0x10000);    // 8MB  [4096][1024] bf16
  ushort_t* H     = (ushort_t*)(ws + 0x810000);   // 32MB [4096][4096] bf16
  ushort_t* W     = (ushort_t*)(ws + 0x2810000);  // 64MB: fct (gemm1), then P (gemm2 partials)
  float* P        = (float*)W;                    // fct dead after gemm1

  hipMemsetAsync(cnt, 0, 32, stream);
  router_kernel<<<NTOK / 32, 256, 0, stream>>>(x, rw, eid, rank, cnt);
  scan_kernel<<<1, 64, 0, stream>>>(cnt, offs, tile_e, tile_m, ntiles);
  gather_kernel<<<NTOK, 256, 0, stream>>>(x, eid, rank, offs, sorted, Xg);
  transpose_fc_kernel<<<dim3(HDIM / 64, DIM / 64, NE), 256, 0, stream>>>(fc, W);
  gemm1_kernel<<<dim3(HDIM / 128, MAXT), 256, 0, stream>>>(Xg, W, offs, tile_e, tile_m, ntiles, H);
  gemm2_kernel<<<dim3(DIM / 128, MAXT, KSPLIT), 256, 0, stream>>>(H, pj, offs, tile_e, tile_m, ntiles, P);
  reduce_kernel<<<NTOK, 256, 0, stream>>>(P, sorted, out);
}

// Round 2
// 470.971 us; speedup vs baseline: 1.0424x; 1.0416x over previous
//
#include <hip/hip_runtime.h>
#include <hip/hip_bf16.h>
#include <stdint.h>

// Problem constants (B=4, T=1024, D=1024, E=8, HD=4096)
#define NE 8
#define DIM 1024
#define HDIM 4096
#define NTOK 4096
#define KSPLIT 4
#define MAXT 40   // max occupied 128-row m-tiles: 32 full + 8 partial

typedef unsigned short ushort_t;
typedef __attribute__((ext_vector_type(4))) float f32x4;
typedef __attribute__((ext_vector_type(8))) short bf16x8;
typedef __attribute__((ext_vector_type(8))) ushort_t u16x8;

#define WAITV4() asm volatile("s_waitcnt vmcnt(4)" ::: "memory")
#define WAITV6() asm volatile("s_waitcnt vmcnt(6)" ::: "memory")
#define WAITV0() asm volatile("s_waitcnt vmcnt(0)" ::: "memory")
#define WAITL0() asm volatile("s_waitcnt lgkmcnt(0)" ::: "memory")
#define SCHEDB() __builtin_amdgcn_sched_barrier(0)
#define BARRIER() __builtin_amdgcn_s_barrier()

// RNE float -> bf16 bits
__device__ __forceinline__ ushort_t f2b(float f) {
  union { float f; unsigned u; } c; c.f = f;
  unsigned u = c.u;
  return (ushort_t)((u + 0x7fffu + ((u >> 16) & 1u)) >> 16);
}

// truncate-pack 2 fp32 -> 2 bf16 in one dword via v_perm
__device__ __forceinline__ unsigned pk2(float a, float b) {
  union { float f; unsigned u; } x, y; x.f = a; y.f = b;
  return __builtin_amdgcn_perm(y.u, x.u, 0x07060302);
}

// async global->LDS, 16 bytes per lane; LDS dest = wave-uniform base + lane*16
__device__ __forceinline__ void gl2lds16(const void* g, void* l) {
  __builtin_amdgcn_global_load_lds(
      (__attribute__((address_space(1))) void*)g,
      (__attribute__((address_space(3))) void*)l, 16, 0, 0);
}

// ---------------- router: logits fp32 + argmax + count (fused) --------------
__global__ __launch_bounds__(256) void router_kernel(
    const float* __restrict__ x, const float* __restrict__ rw,
    int* __restrict__ eid, int* __restrict__ rank, int* __restrict__ cnt) {
  __shared__ float w[NE * 1028];  // stride 1028 to spread LDS banks
  for (int i = threadIdx.x; i < NE * DIM; i += 256) {
    int e = i >> 10, d = i & 1023;
    w[e * 1028 + d] = rw[i];
  }
  __syncthreads();
  int grp = threadIdx.x >> 3;   // 32 tokens / block
  int e = threadIdx.x & 7;      // one expert per lane-in-group
  int t = blockIdx.x * 32 + grp;
  const float4* xr = (const float4*)(x + (size_t)t * DIM);
  const float4* wr = (const float4*)(w + e * 1028);
  float acc = 0.f;
#pragma unroll 4
  for (int i = 0; i < DIM / 4; ++i) {
    float4 xv = xr[i], wv = wr[i];
    acc += xv.x * wv.x + xv.y * wv.y + xv.z * wv.z + xv.w * wv.w;
  }
  float v = acc; int ie = e;
#pragma unroll
  for (int m = 4; m; m >>= 1) {
    float ov = __shfl_xor(v, m, 8);
    int oi = __shfl_xor(ie, m, 8);
    if (ov > v || (ov == v && oi < ie)) { v = ov; ie = oi; }
  }
  if (e == 0) {
    eid[t] = ie;
    rank[t] = atomicAdd(&cnt[ie], 1);
  }
}

// prefix-sum + build dense m-tile table (expert id, row offset within expert)
__global__ void scan_kernel(const int* __restrict__ cnt, int* __restrict__ offs,
                            int* __restrict__ tile_e, int* __restrict__ tile_m,
                            int* __restrict__ ntiles) {
  if (threadIdx.x == 0) {
    int s = 0, nt = 0;
    for (int e = 0; e < NE; ++e) {
      offs[e] = s;
      int c = cnt[e];
      for (int m = 0; m < c; m += 128) { tile_e[nt] = e; tile_m[nt] = m; ++nt; }
      s += c;
    }
    offs[NE] = s;
    *ntiles = nt;
  }
}

// one block per token: write sorted[] and gather x row -> bf16 grouped matrix
__global__ __launch_bounds__(256) void gather_kernel(
    const float* __restrict__ x, const int* __restrict__ eid,
    const int* __restrict__ rank, const int* __restrict__ offs,
    int* __restrict__ sorted, ushort_t* __restrict__ Xg) {
  int t = blockIdx.x;
  int e = eid[t];
  int pos = offs[e] + rank[t];
  if (threadIdx.x == 0) sorted[pos] = t;
  int i = threadIdx.x;  // 256 threads, 4 floats each
  float4 v = ((const float4*)(x + (size_t)t * DIM))[i];
  ushort4 o = make_ushort4(f2b(v.x), f2b(v.y), f2b(v.z), f2b(v.w));
  *(ushort4*)(Xg + (size_t)pos * DIM + i * 4) = o;
}

// ---------------- weight conversion ----------------------------------------
// fc[e][d][h] fp32 -> fct[e][h][d] bf16. 64x64 tiles, float4 reads, 16B writes.
__global__ __launch_bounds__(256) void transpose_fc_kernel(
    const float* __restrict__ fc, ushort_t* __restrict__ fct) {
  __shared__ float tile[64][68];
  int e = blockIdx.z;
  int h0 = blockIdx.x * 64, d0 = blockIdx.y * 64;
  int tid = threadIdx.x;
  int rr = tid >> 4;          // 0..15
  int cc = (tid & 15) * 4;    // 0..60
  const float* src = fc + ((size_t)e * DIM + d0 + rr) * HDIM + h0 + cc;
#pragma unroll
  for (int i = 0; i < 4; ++i) {
    float4 v = *(const float4*)(src + (size_t)(i * 16) * HDIM);
    *(float4*)&tile[rr + i * 16][cc] = v;
  }
  __syncthreads();
  int hr = tid >> 2;          // 0..63
  int dseg = (tid & 3) * 16;  // 0,16,32,48
  union { ushort_t s[16]; u16x8 v[2]; } o;
#pragma unroll
  for (int j = 0; j < 16; ++j) o.s[j] = f2b(tile[dseg + j][hr]);
  ushort_t* dst = fct + ((size_t)e * HDIM + h0 + hr) * DIM + d0 + dseg;
  *(u16x8*)dst = o.v[0];
  *(u16x8*)(dst + 8) = o.v[1];
}

// ---------------- GEMM1: H = relu(Xg @ fct^T)^2, bf16 out -------------------
// C-tile 128x128, 4 waves (2x2), each wave 64x64 = 4x4 of 16x16x32 MFMA.
// Counted-vmcnt 2-deep pipeline (T4): raw barriers, vmcnt(4) per iteration
// (tile t's 4 gl2lds retired, tile t+1's 4 stay in flight), never drained to 0
// in the main loop. Two barriers/iter: publish tile t, then readers-done
// before issuing tile t+2 into the just-freed buffer.
__global__ __launch_bounds__(256, 2) void gemm1_kernel(
    const ushort_t* __restrict__ Xg, const ushort_t* __restrict__ fct,
    const int* __restrict__ offs, const int* __restrict__ tile_e,
    const int* __restrict__ tile_m, const int* __restrict__ ntiles,
    ushort_t* __restrict__ H) {
  // XCD-aware swizzle (T1): grid 32x40=1280, 1280%8==0 -> bijective m157 map.
  int lin = blockIdx.x + 32 * blockIdx.y;
  int sw = (lin & 7) * 160 + (lin >> 3);
  int bx = sw & 31, by = sw >> 5;

  if (by >= *ntiles) return;
  int e = tile_e[by];
  int mb = tile_m[by];   // row offset within expert
  int m0 = offs[e];
  int Me = offs[e + 1] - m0;
  int n0 = bx * 128;

  __shared__ ushort_t As[2][128 * 32];
  __shared__ ushort_t Bs[2][128 * 32];

  int tid = threadIdx.x;
  int wave = tid >> 6;
  int lane = tid & 63;

  const ushort_t* ap[2]; const ushort_t* bp[2];
  int soff[2];
#pragma unroll
  for (int q = 0; q < 2; ++q) {
    int rl = (wave * 2 + q) * 16 + (lane >> 2);
    int kc = (lane & 3) * 8;
    int rg = mb + rl; if (rg >= Me) rg = Me - 1;  // clamp tail rows
    ap[q] = Xg + (size_t)(m0 + rg) * DIM + kc;
    bp[q] = fct + ((size_t)e * HDIM + n0 + rl) * DIM + kc;
    soff[q] = (wave * 2 + q) * 512;
  }

  f32x4 acc[4][4] = {};
  int wm = (wave & 1) * 64;
  int wn = (wave >> 1) * 64;
  int fr = lane & 15;
  int kq = (lane >> 4) * 8;

  // issue order per tile: A0,A1,B0,B1 (4 vmem ops)
  auto stage = [&](int par, int tile) __attribute__((always_inline)) {
    int ko = tile * 32;
    gl2lds16(ap[0] + ko, &As[par][soff[0]]);
    gl2lds16(ap[1] + ko, &As[par][soff[1]]);
    gl2lds16(bp[0] + ko, &Bs[par][soff[0]]);
    gl2lds16(bp[1] + ko, &Bs[par][soff[1]]);
  };

  auto body = [&](int par, int t, bool issue) __attribute__((always_inline)) {
    BARRIER();            // all waves' tile-t gl2lds retired (each waited own vmcnt)
    SCHEDB();             // keep ds_reads below the barrier
    bf16x8 af[4], bf[4];
#pragma unroll
    for (int i = 0; i < 4; ++i) {
      af[i] = *(const bf16x8*)&As[par][(wm + i * 16 + fr) * 32 + kq];
      bf[i] = *(const bf16x8*)&Bs[par][(wn + i * 16 + fr) * 32 + kq];
    }
    WAITL0();             // reads complete before buffer declared free
    SCHEDB();
    BARRIER();            // all readers done -> buf[par] reusable
    if (issue) stage(par, t + 2);
    __builtin_amdgcn_s_setprio(1);
#pragma unroll
    for (int i = 0; i < 4; ++i)
#pragma unroll
      for (int j = 0; j < 4; ++j)
        acc[i][j] = __builtin_amdgcn_mfma_f32_16x16x32_bf16(af[i], bf[j], acc[i][j], 0, 0, 0);
    __builtin_amdgcn_s_setprio(0);
  };

  // prologue: stage tiles 0,1
  stage(0, 0);
  stage(1, 1);
  for (int t = 0; t < 30; ++t) {
    WAITV4();             // tile t retired; tile t+1's 4 stay in flight
    body(t & 1, t, true);
  }
  WAITV4(); body(0, 30, false);
  WAITV0(); body(1, 31, false);

  int cq = (lane >> 4) * 4;
#pragma unroll
  for (int i = 0; i < 4; ++i) {
#pragma unroll
    for (int r = 0; r < 4; ++r) {
      int rl = wm + i * 16 + cq + r;
      int rg = mb + rl;
      if (rg < Me) {
        ushort_t* dst = H + (size_t)(m0 + rg) * HDIM + n0 + wn + (lane & 15);
#pragma unroll
        for (int j = 0; j < 4; ++j) {
          float v = acc[i][j][r];
          v = fmaxf(v, 0.f);
          dst[j * 16] = f2b(v * v);
        }
      }
    }
  }
}

// ---------------- GEMM2: P[ks] = H @ proj^T (K-slice), no atomics -----------
// Same counted-vmcnt 2-deep pipeline. Per tile: 4 B float4 loads (regs) +
// 2 A gl2lds = 6 vmem ops -> vmcnt(6). B pack+ds_write happens at the top of
// the iteration that consumes it (write-late), into the buffer freed two
// iterations ago. Two B register sets, statically indexed (unroll-by-2).
__global__ __launch_bounds__(256, 2) void gemm2_kernel(
    const ushort_t* __restrict__ Hm, const float* __restrict__ pj,
    const int* __restrict__ offs, const int* __restrict__ tile_e,
    const int* __restrict__ tile_m, const int* __restrict__ ntiles,
    float* __restrict__ P) {
  // XCD swizzle: grid 8x40x4 = 1280
  int lin = blockIdx.x + 8 * (blockIdx.y + 40 * blockIdx.z);
  int sw = (lin & 7) * 160 + (lin >> 3);
  int bx = sw & 7, rem = sw >> 3;
  int by = rem % 40, bz = rem / 40;

  if (by >= *ntiles) return;
  int e = tile_e[by];
  int mb = tile_m[by];
  int ks = bz;
  int m0 = offs[e];
  int Me = offs[e + 1] - m0;
  int n0 = bx * 128;

  __shared__ ushort_t As[2][128 * 32];
  __shared__ ushort_t Bs[2][128 * 32];

  int tid = threadIdx.x;
  int wave = tid >> 6;
  int lane = tid & 63;

  int kbeg = ks * (HDIM / KSPLIT);

  // A staging: async 16B, 2 chunks/thread (kbeg folded into base)
  const ushort_t* ap[2]; int soff[2];
#pragma unroll
  for (int q = 0; q < 2; ++q) {
    int rl = (wave * 2 + q) * 16 + (lane >> 2);
    int kc = (lane & 3) * 8;
    int rg = mb + rl; if (rg >= Me) rg = Me - 1;
    ap[q] = Hm + (size_t)(m0 + rg) * HDIM + kc + kbeg;
    soff[q] = (wave * 2 + q) * 512;
  }

  // B staging: thread owns rows {br, br+64}, 8 k each; contiguous 16B LDS writes
  int br = tid >> 2;          // 0..63
  int bk = (tid & 3) * 8;     // 0,8,16,24
  const float* bsrc0 = pj + ((size_t)e * DIM + n0 + br) * HDIM + bk + kbeg;
  const float* bsrc1 = bsrc0 + (size_t)64 * HDIM;
  int boff0 = br * 32 + bk;
  int boff1 = (br + 64) * 32 + bk;

  f32x4 acc[4][4] = {};
  int wm = (wave & 1) * 64;
  int wn = (wave >> 1) * 64;
  int fr = lane & 15;
  int kq = (lane >> 4) * 8;

  // issue order per tile: B0..B3 then A0,A1 (6 vmem ops)
  auto stage = [&](int par, int tile, float4 (&bs)[4]) __attribute__((always_inline)) {
    int ko = tile * 32;
    bs[0] = *(const float4*)(bsrc0 + ko);
    bs[1] = *(const float4*)(bsrc0 + ko + 4);
    bs[2] = *(const float4*)(bsrc1 + ko);
    bs[3] = *(const float4*)(bsrc1 + ko + 4);
    gl2lds16(ap[0] + ko, &As[par][soff[0]]);
    gl2lds16(ap[1] + ko, &As[par][soff[1]]);
  };

  auto body = [&](int par, int t, bool issue, float4 (&bs)[4]) __attribute__((always_inline)) {
    // pack+write tile t's B (loads retired by the vmcnt before this call)
    union { unsigned u[4]; bf16x8 v; } w;
    w.u[0] = pk2(bs[0].x, bs[0].y); w.u[1] = pk2(bs[0].z, bs[0].w);
    w.u[2] = pk2(bs[1].x, bs[1].y); w.u[3] = pk2(bs[1].z, bs[1].w);
    *(bf16x8*)&Bs[par][boff0] = w.v;
    w.u[0] = pk2(bs[2].x, bs[2].y); w.u[1] = pk2(bs[2].z, bs[2].w);
    w.u[2] = pk2(bs[3].x, bs[3].y); w.u[3] = pk2(bs[3].z, bs[3].w);
    *(bf16x8*)&Bs[par][boff1] = w.v;
    WAITL0();             // ds_writes committed to LDS
    BARRIER();            // tile t (A via gl2lds + B via ds_write) published
    SCHEDB();
    bf16x8 af[4], bf[4];
#pragma unroll
    for (int i = 0; i < 4; ++i) {
      af[i] = *(const bf16x8*)&As[par][(wm + i * 16 + fr) * 32 + kq];
      bf[i] = *(const bf16x8*)&Bs[par][(wn + i * 16 + fr) * 32 + kq];
    }
    WAITL0();
    SCHEDB();
    BARRIER();            // readers done -> buf[par] reusable
    if (issue) stage(par, t + 2, bs);
    __builtin_amdgcn_s_setprio(1);
#pragma unroll
    for (int i = 0; i < 4; ++i)
#pragma unroll
      for (int j = 0; j < 4; ++j)
        acc[i][j] = __builtin_amdgcn_mfma_f32_16x16x32_bf16(af[i], bf[j], acc[i][j], 0, 0, 0);
    __builtin_amdgcn_s_setprio(0);
  };

  float4 bsA[4], bsB[4];
  // prologue: stage tiles 0,1
  stage(0, 0, bsA);
  stage(1, 1, bsB);
  for (int t = 0; t < 30; t += 2) {
    WAITV6();             // tile t's 6 retired; tile t+1's 6 in flight
    body(0, t, true, bsA);
    WAITV6();
    body(1, t + 1, true, bsB);
  }
  WAITV6(); body(0, 30, false, bsA);
  WAITV0(); body(1, 31, false, bsB);

  int cq = (lane >> 4) * 4;
#pragma unroll
  for (int i = 0; i < 4; ++i) {
#pragma unroll
    for (int r = 0; r < 4; ++r) {
      int rl = wm + i * 16 + cq + r;
      int rg = mb + rl;
      if (rg < Me) {
        float* dst = P + ((size_t)ks * NTOK + (m0 + rg)) * DIM + n0 + wn + (lane & 15);
#pragma unroll
        for (int j = 0; j < 4; ++j) dst[j * 16] = acc[i][j][r];
      }
    }
  }
}

// ---------------- reduce: out[tok] = sum_ks P[ks][pos], coalesced -----------
__global__ __launch_bounds__(256) void reduce_kernel(
    const float* __restrict__ P, const int* __restrict__ sorted,
    float* __restrict__ out) {
  int pos = blockIdx.x;
  int tok = sorted[pos];
  int i = threadIdx.x;
  size_t base = (size_t)pos * DIM + i * 4;
  const size_t S = (size_t)NTOK * DIM;
  f32x4 s = *(const f32x4*)(P + base) + *(const f32x4*)(P + S + base) +
            *(const f32x4*)(P + 2 * S + base) + *(const f32x4*)(P + 3 * S + base);
  *(f32x4*)(out + (size_t)tok * DIM + i * 4) = s;
}

// ---------------- launch -----------------------------------------------------
extern "C" void kernel_launch(void* const* d_in, const int* in_sizes, int n_in,
                              void* d_out, int out_size, void* d_ws, size_t ws_size,
                              hipStream_t stream) {
  const float* x  = (const float*)d_in[0];
  const float* rw = (const float*)d_in[1];
  const float* fc = (const float*)d_in[2];
  const float* pj = (const float*)d_in[3];
  float* out = (float*)d_out;
  char* ws = (char*)d_ws;

  // workspace layout (~106 MiB, same footprint as prior rounds)
  int* eid        = (int*)(ws + 0x0000);       // 16KB
  int* rank       = (int*)(ws + 0x4000);       // 16KB
  int* cnt        = (int*)(ws + 0x8000);       // 32B
  int* offs       = (int*)(ws + 0x8100);       // 36B
  int* tile_e     = (int*)(ws + 0x8200);       // 160B
  int* tile_m     = (int*)(ws + 0x8600);       // 160B
  int* ntiles     = (int*)(ws + 0x8a00);       // 4B
  int* sorted     = (int*)(ws + 0x9000);       // 16KB
  ushort_t* Xg    = (ushort_t*)(ws + 0x10000);    // 8MB  [4096][1024] bf16
  ushort_t* H     = (ushort_t*)(ws + 0x810000);   // 32MB [4096][4096] bf16
  ushort_t* W     = (ushort_t*)(ws + 0x2810000);  // 64MB: fct (gemm1), then P (gemm2 partials)
  float* P        = (float*)W;                    // fct dead after gemm1

  hipMemsetAsync(cnt, 0, 32, stream);
  router_kernel<<<NTOK / 32, 256, 0, stream>>>(x, rw, eid, rank, cnt);
  scan_kernel<<<1, 64, 0, stream>>>(cnt, offs, tile_e, tile_m, ntiles);
  gather_kernel<<<NTOK, 256, 0, stream>>>(x, eid, rank, offs, sorted, Xg);
  transpose_fc_kernel<<<dim3(HDIM / 64, DIM / 64, NE), 256, 0, stream>>>(fc, W);
  gemm1_kernel<<<dim3(HDIM / 128, MAXT), 256, 0, stream>>>(Xg, W, offs, tile_e, tile_m, ntiles, H);
  gemm2_kernel<<<dim3(DIM / 128, MAXT, KSPLIT), 256, 0, stream>>>(H, pj, offs, tile_e, tile_m, ntiles, P);
  reduce_kernel<<<NTOK, 256, 0, stream>>>(P, sorted, out);
}